// Round 2
// baseline (103.373 us; speedup 1.0000x reference)
//
#include <hip/hip_runtime.h>

#define H 1024
#define NG 65536
#define NSEG 16384

#define BM 256
#define BN 256
#define BK 64
#define NT (H / BK)   // 16 K-tiles

typedef __attribute__((ext_vector_type(8))) short bf16x8;
typedef __attribute__((ext_vector_type(4))) float f32x4;

__device__ __forceinline__ unsigned short f2bf(float x) {
    unsigned u = __builtin_bit_cast(unsigned, x);
    unsigned r = (u + 0x7fffu + ((u >> 16) & 1u)) >> 16;
    return (unsigned short)r;
}

__device__ __forceinline__ void gload_lds16(const void* g, void* l) {
    __builtin_amdgcn_global_load_lds(
        (const __attribute__((address_space(1))) void*)g,
        (__attribute__((address_space(3))) void*)l, 16, 0, 0);
}

#define CFENCE() asm volatile("" ::: "memory")

// ---- Fused setup: convert W to bf16 | init out=proj_b | segment bounds ----
__global__ void setup_kernel(const float* __restrict__ w, unsigned short* __restrict__ wbf,
                             const float* __restrict__ proj_b, float* __restrict__ out,
                             const int* __restrict__ seg, int* __restrict__ seg_start) {
    int b = blockIdx.x;
    if (b < 1024) {
        int i = (b * 256 + threadIdx.x) * 4;
        float4 v = *(const float4*)(w + i);
        ushort4 o;
        o.x = f2bf(v.x); o.y = f2bf(v.y); o.z = f2bf(v.z); o.w = f2bf(v.w);
        *(ushort4*)(wbf + i) = o;
    } else if (b < 1088) {
        int i = (b - 1024) * 256 + threadIdx.x;
        if (i < NSEG) out[i] = proj_b[0];
    } else {
        int g = (b - 1088) * 256 + threadIdx.x;
        if (g > NSEG) return;
        if (g == NSEG) { seg_start[g] = NG; return; }
        int lo = 0, hi = NG;
        while (lo < hi) { int mid = (lo + hi) >> 1; if (seg[mid] < g) lo = mid + 1; else hi = mid; }
        seg_start[g] = lo;
    }
}

// ---- Gather + segment mean -> bf16 h [NSEG, H] ----
__global__ void seg_mean_kernel(const float* __restrict__ hidden,
                                const int* __restrict__ flat_indices,
                                const int* __restrict__ seg_start,
                                unsigned short* __restrict__ hbf) {
    int g = blockIdx.x;
    int t = threadIdx.x;  // 256 threads, 4 floats each
    int s = seg_start[g], e = seg_start[g + 1];
    float4 acc = {0.f, 0.f, 0.f, 0.f};
    for (int i = s; i < e; ++i) {
        int row = flat_indices[i];
        float4 v = *((const float4*)(hidden + (size_t)row * H) + t);
        acc.x += v.x; acc.y += v.y; acc.z += v.z; acc.w += v.w;
    }
    float scale = (e > s) ? 1.0f / (float)(e - s) : 0.0f;
    ushort4 o;
    o.x = f2bf(acc.x * scale); o.y = f2bf(acc.y * scale);
    o.z = f2bf(acc.z * scale); o.w = f2bf(acc.w * scale);
    *(ushort4*)(hbf + (size_t)g * H + t * 4) = o;
}

// ---- 256x256 bf16 MFMA GEMM, double-buffered, counted-vmcnt pipeline ----
__global__ __launch_bounds__(512, 2) void gemm_kernel(
    const unsigned short* __restrict__ Abf,   // h bf16 [NSEG, H]
    const unsigned short* __restrict__ Wbf,   // dense_w bf16 [H, H] (row n contiguous in k)
    const float* __restrict__ dense_b,
    const float* __restrict__ proj_w,
    float* __restrict__ out) {
    __shared__ unsigned short As[2][BM * BK];  // 2 x 32 KB
    __shared__ unsigned short Bs[2][BN * BK];  // 2 x 32 KB
    const int tid = threadIdx.x;
    const int wid = tid >> 6, lane = tid & 63;
    const int wr = wid >> 2, wc = wid & 3;         // wave tile: 128 rows x 64 cols
    const int m0 = blockIdx.x * BM, n0 = blockIdx.y * BN;

    f32x4 acc[8][4] = {};

    // Stage one K-tile: linear LDS dest (chunk index), pre-swizzled global source.
    // LDS row stride = 128B (64 bf16); read-side XOR swizzle = ((row&7)<<4).
    auto STAGE = [&](int buf, int kt) {
#pragma unroll
        for (int it = 0; it < 4; ++it) {
            int c = it * 512 + tid;                 // 16B chunk index, 0..2047
            int row = c >> 3;
            int sw = ((c & 7) << 4) ^ ((row & 7) << 4);
            gload_lds16((const char*)Abf + (((size_t)(m0 + row)) << 11) + kt * 128 + sw,
                        (char*)&As[buf][0] + (it * 512 + wid * 64) * 16);
        }
#pragma unroll
        for (int it = 0; it < 4; ++it) {
            int c = it * 512 + tid;
            int row = c >> 3;
            int sw = ((c & 7) << 4) ^ ((row & 7) << 4);
            gload_lds16((const char*)Wbf + (((size_t)(n0 + row)) << 11) + kt * 128 + sw,
                        (char*)&Bs[buf][0] + (it * 512 + wid * 64) * 16);
        }
    };

    STAGE(0, 0);

    for (int t = 0; t < NT; ++t) {
        // Barrier A: all waves finished reading the buffer we are about to overwrite.
        CFENCE();
        __builtin_amdgcn_s_barrier();
        CFENCE();
        if (t + 1 < NT) {
            STAGE((t + 1) & 1, t + 1);
            asm volatile("s_waitcnt vmcnt(8)" ::: "memory");  // tile t landed; t+1 stays in flight
        } else {
            asm volatile("s_waitcnt vmcnt(0)" ::: "memory");
        }
        // Barrier B: tile t visible to every wave.
        __builtin_amdgcn_s_barrier();
        CFENCE();

        const char* Ab = (const char*)&As[t & 1][0];
        const char* Bb = (const char*)&Bs[t & 1][0];
        __builtin_amdgcn_s_setprio(1);
#pragma unroll
        for (int kk = 0; kk < 2; ++kk) {
            bf16x8 af[8], bw[4];
            int kb = kk * 64 + ((lane >> 4) << 4);
#pragma unroll
            for (int ni = 0; ni < 4; ++ni) {
                int row = wc * 64 + ni * 16 + (lane & 15);
                bw[ni] = *(const bf16x8*)(Bb + row * 128 + (kb ^ ((row & 7) << 4)));
            }
#pragma unroll
            for (int mi = 0; mi < 8; ++mi) {
                int row = wr * 128 + mi * 16 + (lane & 15);
                af[mi] = *(const bf16x8*)(Ab + row * 128 + (kb ^ ((row & 7) << 4)));
            }
#pragma unroll
            for (int mi = 0; mi < 8; ++mi)
#pragma unroll
                for (int ni = 0; ni < 4; ++ni)
                    acc[mi][ni] = __builtin_amdgcn_mfma_f32_16x16x32_bf16(af[mi], bw[ni], acc[mi][ni], 0, 0, 0);
        }
        __builtin_amdgcn_s_setprio(0);
    }

    // Epilogue: z = gelu(acc + b[n]); s += z * proj_w[n]; reduce over the 16 n-lanes.
    float db[4], pw[4];
#pragma unroll
    for (int ni = 0; ni < 4; ++ni) {
        int n = n0 + wc * 64 + ni * 16 + (lane & 15);
        db[ni] = dense_b[n];
        pw[ni] = proj_w[n];
    }
#pragma unroll
    for (int mi = 0; mi < 8; ++mi) {
#pragma unroll
        for (int r = 0; r < 4; ++r) {
            int m = m0 + wr * 128 + mi * 16 + ((lane >> 4) << 2) + r;
            float s = 0.f;
#pragma unroll
            for (int ni = 0; ni < 4; ++ni) {
                float z = acc[mi][ni][r] + db[ni];
                float gl = 0.5f * z * (1.0f + erff(z * 0.70710678118f));
                s += gl * pw[ni];
            }
#pragma unroll
            for (int off = 1; off < 16; off <<= 1) s += __shfl_xor(s, off, 64);
            if ((lane & 15) == 0) atomicAdd(out + m, s);
        }
    }
}

extern "C" void kernel_launch(void* const* d_in, const int* in_sizes, int n_in,
                              void* d_out, int out_size, void* d_ws, size_t ws_size,
                              hipStream_t stream) {
    const float* hidden       = (const float*)d_in[0];
    const float* dense_w      = (const float*)d_in[1];
    const float* dense_b      = (const float*)d_in[2];
    const float* proj_w       = (const float*)d_in[3];
    const float* proj_b       = (const float*)d_in[4];
    const int*   flat_indices = (const int*)d_in[5];
    const int*   segment_ids  = (const int*)d_in[6];
    float* out = (float*)d_out;

    char* ws = (char*)d_ws;
    int* seg_start = (int*)ws;                                   // 16385 ints
    unsigned short* hbf = (unsigned short*)(ws + (1 << 17));     // 32MB
    unsigned short* wbf = (unsigned short*)(ws + (1 << 17) + (size_t)NSEG * H * 2);  // 2MB

    hipLaunchKernelGGL(setup_kernel, dim3(1153), dim3(256), 0, stream,
                       dense_w, wbf, proj_b, out, segment_ids, seg_start);
    hipLaunchKernelGGL(seg_mean_kernel, dim3(NSEG), dim3(256), 0, stream,
                       hidden, flat_indices, seg_start, hbf);
    hipLaunchKernelGGL(gemm_kernel, dim3(NSEG / BM, H / BN), dim3(512), 0, stream,
                       hbf, wbf, dense_b, proj_w, out);
}